// Round 5
// baseline (228.236 us; speedup 1.0000x reference)
//
#include <hip/hip_runtime.h>
#include <math.h>

// Problem constants
#define NCHUNK 256   // B * (H/CS) * (W/CS) = 4*8*8
#define CCH    96
#define DNC    192
#define NST    16
#define DTR    6
#define PROW   48    // padded P row: [0..5]=dts, [8..23]=B, [24..39]=C, rest 0

__device__ __forceinline__ float siluf_(float x) {
    return x / (1.f + __expf(-x));
}

// Direction permutation (involution): xs[k][d][l] = x0[d][sperm(k,l)]
__device__ __forceinline__ int sperm(int k, int l) {
    int t = (k & 1) ? (((l & 7) << 3) | (l >> 3)) : l;
    return (k & 2) ? (63 - t) : t;
}

// ---------------------------------------------------------------- k1a: stats
__global__ void k1a_stats(const float* __restrict__ x, float* __restrict__ stats) {
    int bc = blockIdx.x;                 // b*96 + c
    const float* xp = x + (size_t)bc * 4096;
    float s = 0.f, sq = 0.f;
    for (int i = threadIdx.x; i < 4096; i += 256) {
        float v = xp[i]; s += v; sq += v * v;
    }
    __shared__ float rs[256], rq[256];
    rs[threadIdx.x] = s; rq[threadIdx.x] = sq;
    __syncthreads();
    for (int off = 128; off > 0; off >>= 1) {
        if (threadIdx.x < off) {
            rs[threadIdx.x] += rs[threadIdx.x + off];
            rq[threadIdx.x] += rq[threadIdx.x + off];
        }
        __syncthreads();
    }
    if (threadIdx.x == 0) {
        float m = rs[0] * (1.f / 4096.f);
        float v = rq[0] * (1.f / 4096.f) - m * m;
        stats[bc] = m;
        stats[384 + bc] = rsqrtf(v + 1e-5f);
    }
}

// --------------- ksetup: transpose x_proj_w into padded slot layout
// wTg[k][dd][slot]: slot<6 -> dts c=slot; 8<=slot<40 -> c=slot-2 (B then C); else 0
__global__ void ksetup(const float* __restrict__ xpw, float* __restrict__ wTg) {
    int k = blockIdx.x;
    for (int i = threadIdx.x; i < 192 * PROW; i += 256) {
        int dd = i / PROW, slot = i % PROW;
        int c = -1;
        if (slot < 6) c = slot;
        else if (slot >= 8 && slot < 40) c = slot - 2;
        float v = (c >= 0) ? xpw[((size_t)k * 38 + c) * 192 + dd] : 0.f;
        wTg[((size_t)k * 192 + dd) * PROW + slot] = v;
    }
}

// ------------------------------- kfused: the whole per-chunk pipeline
// LDS: ONE arena, three sequential views:
//   ph1-3: xln[p][c]  at p*97+c   (6,206 f)
//   ph4-6: x0s[d][l]  at d*65+l   (12,479 f)
//   ph7-8: gbuf[p][i] at p*193+i  (12,351 f)
__global__ __launch_bounds__(768, 6) void kfused(
        const float* __restrict__ x, const float* __restrict__ stats,
        const float* __restrict__ gamma, const float* __restrict__ beta,
        const float* __restrict__ ln1_g, const float* __restrict__ ln1_b,
        const float* __restrict__ Win,       // (96,384)
        const float* __restrict__ conv_w, const float* __restrict__ conv_b,
        const float* __restrict__ wTg,       // (4,192,48) slot layout
        const float* __restrict__ dtw, const float* __restrict__ dtb,
        const float* __restrict__ A_logs, const float* __restrict__ Ds,
        const float* __restrict__ og, const float* __restrict__ ob,
        const float* __restrict__ Wout,      // (192,96)
        const float* __restrict__ alpha,
        float* __restrict__ xcg_all,         // [chunk][192][64]; REUSED as yac[l][d]
        float* __restrict__ zg_all,          // [chunk][192][64]
        float* __restrict__ x0g_all,         // [chunk][192][64]
        float* __restrict__ Pg_all,          // [chunk*4+k][64][48]
        float* __restrict__ out) {
    __shared__ float arena[12480];

    int chunk = blockIdx.x;
    int t = threadIdx.x;
    int b = chunk >> 6, chh = (chunk >> 3) & 7, chw = chunk & 7;

    // ---- ph1: load x-chunk, spatial norm + SiLU -> arena(xln view)
    for (int i = t; i < 6144; i += 768) {
        int c = i >> 6, pos = i & 63;
        int bc = b * 96 + c;
        int hh = chh * 8 + (pos >> 3), ww = chw * 8 + (pos & 7);
        float v = x[(((size_t)bc) * 64 + hh) * 64 + ww];
        float xn = (v - stats[bc]) * stats[384 + bc] * gamma[c] + beta[c];
        arena[pos * 97 + c] = siluf_(xn);
    }
    __syncthreads();

    // ---- ph2: LN over 96 per position, in place
    if (t < 512) {
        int p = t >> 3, o = t & 7;
        float s = 0.f, sq = 0.f;
        for (int j = 0; j < 12; j++) { float v = arena[p * 97 + o + 8 * j]; s += v; sq += v * v; }
        s += __shfl_xor(s, 1); sq += __shfl_xor(sq, 1);
        s += __shfl_xor(s, 2); sq += __shfl_xor(sq, 2);
        s += __shfl_xor(s, 4); sq += __shfl_xor(sq, 4);
        float m = s * (1.f / 96.f);
        float rinv = rsqrtf(sq * (1.f / 96.f) - m * m + 1e-5f);
        for (int j = 0; j < 12; j++) {
            int c = o + 8 * j;
            arena[p * 97 + c] = (arena[p * 97 + c] - m) * rinv * ln1_g[c] + ln1_b[c];
        }
    }
    __syncthreads();

    // ---- ph3: in_proj GEMV 96->384; 12 waves x 32 cols (wave-uniform weights)
    {
        int p = t & 63;
        int wv = __builtin_amdgcn_readfirstlane(t >> 6);   // 0..11
        int jbase = wv * 32;
        float acc[32];
        #pragma unroll
        for (int i = 0; i < 32; i++) acc[i] = 0.f;
        for (int c = 0; c < 96; c++) {
            float u = arena[p * 97 + c];
            const float* w = Win + c * 384 + jbase;        // scalar loads
            #pragma unroll
            for (int i = 0; i < 32; i++) acc[i] = fmaf(u, w[i], acc[i]);
        }
        if (jbase < 192) {          // conv-input half -> global xcg[d][p]
            float* xg = xcg_all + (size_t)chunk * 12288 + jbase * 64 + p;
            #pragma unroll
            for (int i = 0; i < 32; i++) xg[i * 64] = acc[i];
        } else {                    // z half -> global [j][p]
            float* zg = zg_all + (size_t)chunk * 12288 + (jbase - 192) * 64 + p;
            #pragma unroll
            for (int i = 0; i < 32; i++) zg[i * 64] = acc[i];
        }
    }
    __syncthreads();   // drains stores; ph4 reads xcg via L2

    // ---- ph4: depthwise 3x3 conv + bias + SiLU -> arena(x0s) + x0g
    {
        const float* xg = xcg_all + (size_t)chunk * 12288;
        float* x0g = x0g_all + (size_t)chunk * 12288;
        for (int s = 0; s < 16; s++) {
            int o = t + s * 768;
            int d = o >> 6, l = o & 63;
            int r = l >> 3, cc = l & 7;
            float acc = conv_b[d];
            #pragma unroll
            for (int dh = 0; dh < 3; dh++) {
                int rr = r + dh - 1;
                if (rr < 0 || rr > 7) continue;
                #pragma unroll
                for (int dw = 0; dw < 3; dw++) {
                    int cw = cc + dw - 1;
                    if (cw < 0 || cw > 7) continue;
                    acc = fmaf(xg[d * 64 + rr * 8 + cw], conv_w[d * 9 + dh * 3 + dw], acc);
                }
            }
            float v = siluf_(acc);
            arena[d * 65 + l] = v;
            x0g[o] = v;
        }
    }
    __syncthreads();

    // ---- ph5: P-projection -> Pg (slot layout); zero yac (aliases dead xcg)
    {
        int k = __builtin_amdgcn_readfirstlane(t / 192);
        int tk = t - k * 192;
        int l = tk & 63;
        int cg = __builtin_amdgcn_readfirstlane(tk >> 6);  // 0..2
        int cbase = cg * 16;
        float acc[16];
        #pragma unroll
        for (int i = 0; i < 16; i++) acc[i] = 0.f;
        for (int dd = 0; dd < 192; dd++) {
            float u = arena[dd * 65 + l];
            const float* w = wTg + ((size_t)k * 192 + dd) * PROW + cbase;  // scalar
            #pragma unroll
            for (int i = 0; i < 16; i++) acc[i] = fmaf(u, w[i], acc[i]);
        }
        float* pg = Pg_all + (size_t)(chunk * 4 + k) * 3072 + l * PROW + cbase;
        #pragma unroll
        for (int i = 0; i < 16; i += 4)
            *(float4*)(pg + i) = make_float4(acc[i], acc[i+1], acc[i+2], acc[i+3]);
    }
    {   // zero yac (xcg region, dead after ph4)
        float* yac = xcg_all + (size_t)chunk * 12288;
        for (int i = t; i < 12288; i += 768) yac[i] = 0.f;
    }
    __syncthreads();   // drains Pg + zeroing before s_loads / atomics

    // ---- ph6: selective scan, 4 direction-groups; merge via global f32 atomics
    {
        int k = __builtin_amdgcn_readfirstlane(t / 192);
        int d = t - k * 192;
        int gd = k * 192 + d;
        float* yac = xcg_all + (size_t)chunk * 12288;      // [l][d]
        float w6[6];
        #pragma unroll
        for (int r = 0; r < 6; r++) w6[r] = dtw[gd * 6 + r];
        float bias = dtb[gd];
        float a[16];
        #pragma unroll
        for (int n = 0; n < 16; n++) a[n] = -__expf(A_logs[gd * 16 + n]);
        bool pw = true;
        #pragma unroll
        for (int n = 1; n < 16; n++)
            pw = pw && (fabsf(a[n] - (float)(n + 1) * a[0]) <= 1e-4f * fabsf(a[n]) + 1e-6f);
        float hst[16];
        #pragma unroll
        for (int n = 0; n < 16; n++) hst[n] = 0.f;
        const float* pbase = Pg_all + (size_t)(chunk * 4 + k) * 3072;  // uniform

        if (__all(pw)) {
            float a0 = a[0];
            for (int l = 0; l < 64; l++) {
                int sl = sperm(k, l);
                const float* row = pbase + sl * PROW;   // uniform -> s_load
                float u = arena[d * 65 + sl];
                float dp = bias;
                #pragma unroll
                for (int r = 0; r < 6; r++) dp = fmaf(row[r], w6[r], dp);
                float ex = __expf(dp);
                float delta = (dp > 20.f) ? dp : __logf(1.f + ex);
                float du = delta * u;
                float e1 = __expf(delta * a0);
                float p[16];
                p[0] = e1;
                p[1] = e1 * e1;
                p[2] = p[1] * e1;   p[3] = p[1] * p[1];
                p[4] = p[3] * e1;   p[5] = p[3] * p[1];
                p[6] = p[3] * p[2]; p[7] = p[3] * p[3];
                p[8] = p[7] * e1;   p[9] = p[7] * p[1];
                p[10] = p[7] * p[2]; p[11] = p[7] * p[3];
                p[12] = p[7] * p[4]; p[13] = p[7] * p[5];
                p[14] = p[7] * p[6]; p[15] = p[7] * p[7];
                float y0 = 0.f, y1 = 0.f, y2 = 0.f, y3 = 0.f;
                #pragma unroll
                for (int n = 0; n < 16; n += 4) {
                    hst[n]     = fmaf(hst[n],     p[n],     du * row[8 + n]);
                    hst[n + 1] = fmaf(hst[n + 1], p[n + 1], du * row[9 + n]);
                    hst[n + 2] = fmaf(hst[n + 2], p[n + 2], du * row[10 + n]);
                    hst[n + 3] = fmaf(hst[n + 3], p[n + 3], du * row[11 + n]);
                    y0 = fmaf(hst[n],     row[24 + n], y0);
                    y1 = fmaf(hst[n + 1], row[25 + n], y1);
                    y2 = fmaf(hst[n + 2], row[26 + n], y2);
                    y3 = fmaf(hst[n + 3], row[27 + n], y3);
                }
                atomicAdd(&yac[sl * 192 + d], (y0 + y1) + (y2 + y3));
            }
        } else {
            for (int l = 0; l < 64; l++) {
                int sl = sperm(k, l);
                const float* row = pbase + sl * PROW;
                float u = arena[d * 65 + sl];
                float dp = bias;
                #pragma unroll
                for (int r = 0; r < 6; r++) dp = fmaf(row[r], w6[r], dp);
                float ex = __expf(dp);
                float delta = (dp > 20.f) ? dp : __logf(1.f + ex);
                float du = delta * u;
                float y = 0.f;
                #pragma unroll
                for (int n = 0; n < 16; n++) {
                    float e = __expf(delta * a[n]);
                    hst[n] = fmaf(hst[n], e, du * row[8 + n]);
                    y = fmaf(hst[n], row[24 + n], y);
                }
                atomicAdd(&yac[sl * 192 + d], y);
            }
        }
    }
    __syncthreads();   // drains atomics; arena(x0s) now dead

    // ---- ph7: outnorm LN(192) + D-term + silu(z) gate -> arena(gbuf view)
    if (t < 512) {
        int p = t >> 3, o = t & 7;
        const float* yac = xcg_all + (size_t)chunk * 12288;
        const float* x0g = x0g_all + (size_t)chunk * 12288;
        const float* zg  = zg_all  + (size_t)chunk * 12288;
        float ys[24];
        float s = 0.f, sq = 0.f;
        #pragma unroll
        for (int j = 0; j < 24; j++) {
            int i = o + 8 * j;
            float dsum = Ds[i] + Ds[192 + i] + Ds[384 + i] + Ds[576 + i];
            float v = yac[p * 192 + i] + dsum * x0g[i * 64 + p];
            ys[j] = v;
            s += v; sq += v * v;
        }
        s += __shfl_xor(s, 1); sq += __shfl_xor(sq, 1);
        s += __shfl_xor(s, 2); sq += __shfl_xor(sq, 2);
        s += __shfl_xor(s, 4); sq += __shfl_xor(sq, 4);
        float m = s * (1.f / 192.f);
        float rinv = rsqrtf(sq * (1.f / 192.f) - m * m + 1e-5f);
        #pragma unroll
        for (int j = 0; j < 24; j++) {
            int i = o + 8 * j;
            float ln = (ys[j] - m) * rinv * og[i] + ob[i];
            arena[p * 193 + i] = ln * siluf_(zg[i * 64 + p]);
        }
    }
    __syncthreads();

    // ---- ph8: out_proj GEMV 192->96 + recomputed h residual + final blend
    {
        int p = t & 63;
        int wv = __builtin_amdgcn_readfirstlane(t >> 6);   // 0..11
        int cbase = wv * 8;
        float acc[8];
        #pragma unroll
        for (int i = 0; i < 8; i++) acc[i] = 0.f;
        for (int dd = 0; dd < 192; dd++) {
            float u = arena[p * 193 + dd];
            const float* w = Wout + dd * 96 + cbase;       // scalar loads
            #pragma unroll
            for (int i = 0; i < 8; i++) acc[i] = fmaf(u, w[i], acc[i]);
        }
        float al = alpha[0];
        int hh = chh * 8 + (p >> 3), ww = chw * 8 + (p & 7);
        #pragma unroll
        for (int i = 0; i < 8; i++) {
            int c = cbase + i;
            int bc = b * 96 + c;
            size_t gi = (((size_t)bc) * 64 + hh) * 64 + ww;
            float xv = x[gi];
            float xn = (xv - stats[bc]) * stats[384 + bc] * gamma[c] + beta[c];
            float hval = siluf_(xn);                       // recomputed residual h
            float hnew = hval + acc[i];
            out[gi] = xv + al * hnew;
        }
    }
}

extern "C" void kernel_launch(void* const* d_in, const int* in_sizes, int n_in,
                              void* d_out, int out_size, void* d_ws, size_t ws_size,
                              hipStream_t stream) {
    const float* x        = (const float*)d_in[0];
    const float* gamma    = (const float*)d_in[1];
    const float* beta     = (const float*)d_in[2];
    const float* alpha    = (const float*)d_in[3];
    const float* ln1_g    = (const float*)d_in[4];
    const float* ln1_b    = (const float*)d_in[5];
    const float* in_proj  = (const float*)d_in[6];
    const float* conv_w   = (const float*)d_in[7];
    const float* conv_b   = (const float*)d_in[8];
    const float* x_proj   = (const float*)d_in[9];
    const float* dt_w     = (const float*)d_in[10];
    const float* dt_b     = (const float*)d_in[11];
    const float* A_logs   = (const float*)d_in[12];
    const float* Ds       = (const float*)d_in[13];
    const float* onorm_g  = (const float*)d_in[14];
    const float* onorm_b  = (const float*)d_in[15];
    const float* out_proj = (const float*)d_in[16];
    float* out = (float*)d_out;

    float* ws    = (float*)d_ws;
    float* stats = ws;                      // 768 f
    float* wTg   = ws + 768;                // 36,864 f
    float* xcg   = wTg + 36864;             // 3,145,728 f  (reused as yac)
    float* zg    = xcg + 3145728;           // 3,145,728 f
    float* x0g   = zg + 3145728;            // 3,145,728 f
    float* Pg    = x0g + 3145728;           // 786,432 f    (total ~41 MB)

    hipLaunchKernelGGL(k1a_stats, dim3(384), dim3(256), 0, stream, x, stats);
    hipLaunchKernelGGL(ksetup, dim3(4), dim3(256), 0, stream, x_proj, wTg);
    hipLaunchKernelGGL(kfused, dim3(256), dim3(768), 0, stream,
                       x, stats, gamma, beta, ln1_g, ln1_b, in_proj,
                       conv_w, conv_b, wTg, dt_w, dt_b, A_logs, Ds,
                       onorm_g, onorm_b, out_proj, alpha,
                       xcg, zg, x0g, Pg, out);
}

// Round 6
// 227.038 us; speedup vs baseline: 1.0053x; 1.0053x over previous
//
#include <hip/hip_runtime.h>
#include <math.h>

// Problem constants
#define NCHUNK 256   // B * (H/CS) * (W/CS) = 4*8*8
#define PROW   40    // P row: [0..5]=dts, [8..23]=B, [24..39]=C

__device__ __forceinline__ float siluf_(float x) {
    return x / (1.f + __expf(-x));
}

// Direction permutation (involution): xs[k][d][l] = x0[d][sperm(k,l)]
__device__ __forceinline__ int sperm(int k, int l) {
    int t = (k & 1) ? (((l & 7) << 3) | (l >> 3)) : l;
    return (k & 2) ? (63 - t) : t;
}

// ---------------------------------------------------------------- k1a: stats
__global__ void k1a_stats(const float* __restrict__ x, float* __restrict__ stats) {
    int bc = blockIdx.x;                 // b*96 + c
    const float* xp = x + (size_t)bc * 4096;
    float s = 0.f, sq = 0.f;
    for (int i = threadIdx.x; i < 4096; i += 256) {
        float v = xp[i]; s += v; sq += v * v;
    }
    __shared__ float rs[256], rq[256];
    rs[threadIdx.x] = s; rq[threadIdx.x] = sq;
    __syncthreads();
    for (int off = 128; off > 0; off >>= 1) {
        if (threadIdx.x < off) {
            rs[threadIdx.x] += rs[threadIdx.x + off];
            rq[threadIdx.x] += rq[threadIdx.x + off];
        }
        __syncthreads();
    }
    if (threadIdx.x == 0) {
        float m = rs[0] * (1.f / 4096.f);
        float v = rq[0] * (1.f / 4096.f) - m * m;
        stats[bc] = m;
        stats[384 + bc] = rsqrtf(v + 1e-5f);
    }
}

// ---- kA: spatial-norm+SiLU + LN(96) + in_proj cols [cg*96, cg*96+96)
// grid 1024 = chunk*4; block 256. Each block redundantly does norm+LN (cheap).
__global__ __launch_bounds__(256) void kA(
        const float* __restrict__ x, const float* __restrict__ stats,
        const float* __restrict__ gamma, const float* __restrict__ beta,
        const float* __restrict__ ln1_g, const float* __restrict__ ln1_b,
        const float* __restrict__ Win,       // (96,384)
        float* __restrict__ xcg_all,         // [chunk][192][64]
        float* __restrict__ zg_all) {        // [chunk][192][64]
    int blk = blockIdx.x;
    int chunk = blk >> 2, cg = blk & 3;
    int b = chunk >> 6, chh = (chunk >> 3) & 7, chw = chunk & 7;
    __shared__ float hs[64 * 97];
    int t = threadIdx.x;
    for (int i = t; i < 6144; i += 256) {
        int c = i >> 6, pos = i & 63;
        int bc = b * 96 + c;
        int hh = chh * 8 + (pos >> 3), ww = chw * 8 + (pos & 7);
        float v = x[(((size_t)bc) * 64 + hh) * 64 + ww];
        float xn = (v - stats[bc]) * stats[384 + bc] * gamma[c] + beta[c];
        hs[pos * 97 + c] = siluf_(xn);
    }
    __syncthreads();
    {   // LN over 96: 4 lanes per position
        int p = t >> 2, o = t & 3;
        float s = 0.f, sq = 0.f;
        #pragma unroll
        for (int j = 0; j < 24; j++) { float v = hs[p * 97 + o + 4 * j]; s += v; sq += v * v; }
        s += __shfl_xor(s, 1); sq += __shfl_xor(sq, 1);
        s += __shfl_xor(s, 2); sq += __shfl_xor(sq, 2);
        float m = s * (1.f / 96.f);
        float rinv = rsqrtf(sq * (1.f / 96.f) - m * m + 1e-5f);
        #pragma unroll
        for (int j = 0; j < 24; j++) {
            int c = o + 4 * j;
            hs[p * 97 + c] = (hs[p * 97 + c] - m) * rinv * ln1_g[c] + ln1_b[c];
        }
    }
    __syncthreads();
    int p = t & 63;
    int wv = __builtin_amdgcn_readfirstlane(t >> 6);   // 0..3
    int jbase = cg * 96 + wv * 24;
    float acc[24];
    #pragma unroll
    for (int i = 0; i < 24; i++) acc[i] = 0.f;
    for (int c = 0; c < 96; c++) {
        float u = hs[p * 97 + c];
        const float* w = Win + c * 384 + jbase;        // wave-uniform -> s_load
        #pragma unroll
        for (int i = 0; i < 24; i++) acc[i] = fmaf(u, w[i], acc[i]);
    }
    if (jbase < 192) {
        float* o_ = xcg_all + (size_t)chunk * 12288 + jbase * 64 + p;
        #pragma unroll
        for (int i = 0; i < 24; i++) o_[i * 64] = acc[i];
    } else {
        float* o_ = zg_all + (size_t)chunk * 12288 + (jbase - 192) * 64 + p;
        #pragma unroll
        for (int i = 0; i < 24; i++) o_[i * 64] = acc[i];
    }
}

// ---- kB: depthwise 3x3 + bias + SiLU; channels [dg*48, dg*48+48) -> x0T[l][d]
__global__ __launch_bounds__(256) void kB(
        const float* __restrict__ xcg_all, const float* __restrict__ conv_w,
        const float* __restrict__ conv_b, float* __restrict__ x0T_all) {
    int blk = blockIdx.x;
    int chunk = blk >> 2, dg = blk & 3;
    int dbase = dg * 48;
    __shared__ float tile[48 * 65];
    int t = threadIdx.x;
    const float* in = xcg_all + (size_t)chunk * 12288 + dbase * 64;
    for (int i = t; i < 3072; i += 256) tile[(i >> 6) * 65 + (i & 63)] = in[i];
    __syncthreads();
    float* o = x0T_all + (size_t)chunk * 12288;
    for (int s = 0; s < 12; s++) {
        int idx = s * 256 + t;                 // < 3072
        int l = idx / 48, dl = idx - l * 48;
        int r = l >> 3, cc = l & 7;
        int d = dbase + dl;
        float acc = conv_b[d];
        #pragma unroll
        for (int dh = 0; dh < 3; dh++) {
            int rr = r + dh - 1;
            if (rr < 0 || rr > 7) continue;
            #pragma unroll
            for (int dw = 0; dw < 3; dw++) {
                int cw = cc + dw - 1;
                if (cw < 0 || cw > 7) continue;
                acc = fmaf(tile[dl * 65 + rr * 8 + cw], conv_w[d * 9 + dh * 3 + dw], acc);
            }
        }
        o[l * 192 + d] = siluf_(acc);          // 48-wide bursts
    }
}

// ---- kD: per (chunk,k): x_proj GEMV -> Pg, then selective scan w/ s_load rows
// grid 1024, 192 threads, LDS 10.5 KB
__global__ __launch_bounds__(192) void kD(
        const float* __restrict__ x0T_all, const float* __restrict__ xpw, // (4,38,192)
        const float* __restrict__ dtw, const float* __restrict__ dtb,
        const float* __restrict__ A_logs, const float* __restrict__ Ds,
        float* __restrict__ Pg_all,          // [blk][64][40]
        float* __restrict__ yac_all) {       // [chunk][64][192], pre-zeroed
    int blk = blockIdx.x;
    int chunk = blk >> 2, k = blk & 3;
    __shared__ float pT[64 * 41];
    int t = threadIdx.x;
    const float* xbase = x0T_all + (size_t)chunk * 12288;

    // phase 1: P[c][l] = sum_dd xpw[k][c][dd] * x0[dd at pos l]
    {
        int l = t & 63;
        int wv = __builtin_amdgcn_readfirstlane(t >> 6);  // 0..2
        int cbase = wv * 13;
        float acc[13];
        #pragma unroll
        for (int i = 0; i < 13; i++) acc[i] = 0.f;
        const float* xl = xbase + l * 192;
        const float* wb = xpw + (size_t)k * 38 * 192;
        for (int dd = 0; dd < 192; dd += 4) {
            float4 u4 = *(const float4*)(xl + dd);        // per-lane contiguous
            #pragma unroll
            for (int ci = 0; ci < 13; ci++) {
                int c = cbase + ci;
                if (c < 38) {
                    float4 w4 = *(const float4*)(wb + c * 192 + dd);  // uniform -> s_load
                    acc[ci] = fmaf(u4.x, w4.x, acc[ci]);
                    acc[ci] = fmaf(u4.y, w4.y, acc[ci]);
                    acc[ci] = fmaf(u4.z, w4.z, acc[ci]);
                    acc[ci] = fmaf(u4.w, w4.w, acc[ci]);
                }
            }
        }
        #pragma unroll
        for (int ci = 0; ci < 13; ci++) {
            int c = cbase + ci;
            if (c < 38) {
                int slot = c + (c >= 6 ? 2 : 0);
                pT[l * 41 + slot] = acc[ci];
            }
        }
    }
    __syncthreads();
    float* pgout = Pg_all + (size_t)blk * 2560;
    for (int i = t; i < 2560; i += 192) {
        int l = i / 40, s = i - l * 40;
        pgout[i] = pT[l * 41 + s];                        // coalesced
    }
    __syncthreads();   // drains stores before s_loads

    // phase 2: scan; thread = channel d
    {
        int d = t;                                        // 0..191
        int gd = k * 192 + d;
        float w6[6];
        #pragma unroll
        for (int r = 0; r < 6; r++) w6[r] = dtw[gd * 6 + r];
        float bias = dtb[gd];
        float Dd = Ds[gd];
        float a[16];
        #pragma unroll
        for (int n = 0; n < 16; n++) a[n] = -__expf(A_logs[gd * 16 + n]);
        bool pw = true;
        #pragma unroll
        for (int n = 1; n < 16; n++)
            pw = pw && (fabsf(a[n] - (float)(n + 1) * a[0]) <= 1e-4f * fabsf(a[n]) + 1e-6f);
        float hst[16];
        #pragma unroll
        for (int n = 0; n < 16; n++) hst[n] = 0.f;
        const float* pbase = pgout;
        float* yo = yac_all + (size_t)chunk * 12288;

        if (__all(pw)) {
            float a0 = a[0];
            float u_nxt = xbase[sperm(k, 0) * 192 + d];
            for (int l = 0; l < 64; l++) {
                int sl = sperm(k, l);
                float u = u_nxt;
                if (l < 63) u_nxt = xbase[sperm(k, l + 1) * 192 + d];   // prefetch
                const float* row = pbase + sl * PROW;     // uniform -> s_load
                float dp = bias;
                #pragma unroll
                for (int r = 0; r < 6; r++) dp = fmaf(row[r], w6[r], dp);
                float delta = (dp > 20.f) ? dp : __logf(1.f + __expf(dp));
                float du = delta * u;
                float e1 = __expf(delta * a0);
                float p[16];
                p[0] = e1;
                p[1] = e1 * e1;
                p[2] = p[1] * e1;   p[3] = p[1] * p[1];
                p[4] = p[3] * e1;   p[5] = p[3] * p[1];
                p[6] = p[3] * p[2]; p[7] = p[3] * p[3];
                p[8] = p[7] * e1;   p[9] = p[7] * p[1];
                p[10] = p[7] * p[2]; p[11] = p[7] * p[3];
                p[12] = p[7] * p[4]; p[13] = p[7] * p[5];
                p[14] = p[7] * p[6]; p[15] = p[7] * p[7];
                float y0 = 0.f, y1 = 0.f, y2 = 0.f, y3 = 0.f;
                #pragma unroll
                for (int n = 0; n < 16; n += 4) {
                    hst[n]     = fmaf(hst[n],     p[n],     du * row[8 + n]);
                    hst[n + 1] = fmaf(hst[n + 1], p[n + 1], du * row[9 + n]);
                    hst[n + 2] = fmaf(hst[n + 2], p[n + 2], du * row[10 + n]);
                    hst[n + 3] = fmaf(hst[n + 3], p[n + 3], du * row[11 + n]);
                    y0 = fmaf(hst[n],     row[24 + n], y0);
                    y1 = fmaf(hst[n + 1], row[25 + n], y1);
                    y2 = fmaf(hst[n + 2], row[26 + n], y2);
                    y3 = fmaf(hst[n + 3], row[27 + n], y3);
                }
                atomicAdd(&yo[sl * 192 + d], (y0 + y1) + (y2 + y3) + Dd * u);
            }
        } else {
            for (int l = 0; l < 64; l++) {
                int sl = sperm(k, l);
                float u = xbase[sl * 192 + d];
                const float* row = pbase + sl * PROW;
                float dp = bias;
                #pragma unroll
                for (int r = 0; r < 6; r++) dp = fmaf(row[r], w6[r], dp);
                float delta = (dp > 20.f) ? dp : __logf(1.f + __expf(dp));
                float du = delta * u;
                float y = 0.f;
                #pragma unroll
                for (int n = 0; n < 16; n++) {
                    float e = __expf(delta * a[n]);
                    hst[n] = fmaf(hst[n], e, du * row[8 + n]);
                    y = fmaf(hst[n], row[24 + n], y);
                }
                atomicAdd(&yo[sl * 192 + d], y + Dd * u);
            }
        }
    }
}

// ---- kE: outnorm LN(192) + silu(z) gate -> g[dd][p]; grid 512 (chunk-half)
__global__ __launch_bounds__(256) void kE(
        const float* __restrict__ yac_all, const float* __restrict__ zg_all,
        const float* __restrict__ og, const float* __restrict__ ob,
        float* __restrict__ g_all) {
    int blk = blockIdx.x;
    int chunk = blk >> 1, half = blk & 1;
    int t = threadIdx.x;
    int p = half * 32 + (t >> 3), o = t & 7;
    const float* yrow = yac_all + (size_t)chunk * 12288 + p * 192;
    float ys[24];
    float s = 0.f, sq = 0.f;
    #pragma unroll
    for (int j = 0; j < 24; j++) {
        float v = yrow[o + 8 * j];
        ys[j] = v; s += v; sq += v * v;
    }
    s += __shfl_xor(s, 1); sq += __shfl_xor(sq, 1);
    s += __shfl_xor(s, 2); sq += __shfl_xor(sq, 2);
    s += __shfl_xor(s, 4); sq += __shfl_xor(sq, 4);
    float m = s * (1.f / 192.f);
    float rinv = rsqrtf(sq * (1.f / 192.f) - m * m + 1e-5f);
    const float* z = zg_all + (size_t)chunk * 12288;
    float* g = g_all + (size_t)chunk * 12288;
    #pragma unroll
    for (int j = 0; j < 24; j++) {
        int i = o + 8 * j;
        float ln = (ys[j] - m) * rinv * og[i] + ob[i];
        g[i * 64 + p] = ln * siluf_(z[i * 64 + p]);
    }
}

// ---- kF: out_proj GEMV 192->96 (cols cg*24..+24) + residual recompute + blend
__global__ __launch_bounds__(256) void kF(
        const float* __restrict__ g_all, const float* __restrict__ Wout,  // (192,96)
        const float* __restrict__ x, const float* __restrict__ stats,
        const float* __restrict__ gamma, const float* __restrict__ beta,
        const float* __restrict__ alpha, float* __restrict__ out) {
    int blk = blockIdx.x;
    int chunk = blk >> 2, cgf = blk & 3;
    int b = chunk >> 6, chh = (chunk >> 3) & 7, chw = chunk & 7;
    int t = threadIdx.x;
    int p = t & 63;
    int wv = __builtin_amdgcn_readfirstlane(t >> 6);   // 0..3
    int cbase = cgf * 24 + wv * 6;
    float acc[6];
    #pragma unroll
    for (int i = 0; i < 6; i++) acc[i] = 0.f;
    const float* g = g_all + (size_t)chunk * 12288;
    for (int dd = 0; dd < 192; dd++) {
        float u = g[dd * 64 + p];                      // coalesced, L1-shared
        const float* w = Wout + dd * 96 + cbase;       // uniform -> s_load
        #pragma unroll
        for (int i = 0; i < 6; i++) acc[i] = fmaf(u, w[i], acc[i]);
    }
    float al = alpha[0];
    int hh = chh * 8 + (p >> 3), ww = chw * 8 + (p & 7);
    #pragma unroll
    for (int i = 0; i < 6; i++) {
        int c = cbase + i;
        int bc = b * 96 + c;
        size_t gi = (((size_t)bc) * 64 + hh) * 64 + ww;
        float xv = x[gi];
        float xn = (xv - stats[bc]) * stats[384 + bc] * gamma[c] + beta[c];
        out[gi] = xv + al * (siluf_(xn) + acc[i]);
    }
}

extern "C" void kernel_launch(void* const* d_in, const int* in_sizes, int n_in,
                              void* d_out, int out_size, void* d_ws, size_t ws_size,
                              hipStream_t stream) {
    const float* x        = (const float*)d_in[0];
    const float* gamma    = (const float*)d_in[1];
    const float* beta     = (const float*)d_in[2];
    const float* alpha    = (const float*)d_in[3];
    const float* ln1_g    = (const float*)d_in[4];
    const float* ln1_b    = (const float*)d_in[5];
    const float* in_proj  = (const float*)d_in[6];
    const float* conv_w   = (const float*)d_in[7];
    const float* conv_b   = (const float*)d_in[8];
    const float* x_proj   = (const float*)d_in[9];
    const float* dt_w     = (const float*)d_in[10];
    const float* dt_b     = (const float*)d_in[11];
    const float* A_logs   = (const float*)d_in[12];
    const float* Ds       = (const float*)d_in[13];
    const float* onorm_g  = (const float*)d_in[14];
    const float* onorm_b  = (const float*)d_in[15];
    const float* out_proj = (const float*)d_in[16];
    float* out = (float*)d_out;

    float* ws    = (float*)d_ws;
    float* stats = ws;                      // 768 f
    float* xcg   = ws + 768;                // 3,145,728 f ; REUSED as yac after kB
    float* zg    = xcg + 3145728;           // 3,145,728 f
    float* x0T   = zg + 3145728;            // 3,145,728 f ; REUSED as g after kD
    float* Pg    = x0T + 3145728;           // 1024*2560 = 2,621,440 f  (~48.2 MB total)
    float* yac   = xcg;                     // alias (xcg dead after kB; memset between)
    float* gbuf  = x0T;                     // alias (x0T dead after kD)

    hipLaunchKernelGGL(k1a_stats, dim3(384), dim3(256), 0, stream, x, stats);
    hipLaunchKernelGGL(kA, dim3(1024), dim3(256), 0, stream,
                       x, stats, gamma, beta, ln1_g, ln1_b, in_proj, xcg, zg);
    hipLaunchKernelGGL(kB, dim3(1024), dim3(256), 0, stream,
                       xcg, conv_w, conv_b, x0T);
    hipMemsetAsync(yac, 0, (size_t)3145728 * 4, stream);   // yac = 0 (aliases xcg)
    hipLaunchKernelGGL(kD, dim3(1024), dim3(192), 0, stream,
                       x0T, x_proj, dt_w, dt_b, A_logs, Ds, Pg, yac);
    hipLaunchKernelGGL(kE, dim3(512), dim3(256), 0, stream,
                       yac, zg, onorm_g, onorm_b, gbuf);
    hipLaunchKernelGGL(kF, dim3(1024), dim3(256), 0, stream,
                       gbuf, out_proj, x, stats, gamma, beta, alpha, out);
}